// Round 7
// baseline (109.597 us; speedup 1.0000x reference)
//
#include <hip/hip_runtime.h>

// Problem constants: B=4, C=32, H=W=256, heads=4, head_dim=8, amp=2.
#define Bdim 4
#define Cdim 32
#define NH   4
#define HD   8
#define Hdim 256
#define Wdim 256
#define AMP  2
#define KS   5

// R7: R6 structure + NON-TEMPORAL loads/stores. Kernel pinned at ~18us across
// occupancy 50->100% (R1/R2), request bytes -18% (R6), pipeline (R3-5, worse).
// Theory: harness poison fills (536MB/iter) leave L3 full of DIRTY lines; our
// ~66MB of read misses allocate -> evict -> ~66MB poison writeback INSIDE our
// window => ~132MB kernel-window HBM ~= 18-21us. nt loads (evict-first /
// no-allocate) dodge the writeback tax; q has no reuse, k halo reuse is in
// LDS, out never re-read. Single-variable change vs R6.
#define XT    32
#define TY    8
#define TROWS 12                    // TY + 2*AMP
#define TPOS  40
#define NPAIRS 16                   // 4 heads * 4 d-pairs
#define PAIR_STRIDE (TROWS * TPOS)  // 480
#define TILE_SLOTS (NPAIRS * PAIR_STRIDE)   // 7680 * 4B = 30 KB
#define NJOBS (NPAIRS * TROWS * 10) // 1920 float4 staging jobs

typedef _Float16 h2 __attribute__((ext_vector_type(2)));
typedef float f32x4 __attribute__((ext_vector_type(4)));
typedef float f32x2 __attribute__((ext_vector_type(2)));

#define NTLOAD4(p) __builtin_nontemporal_load((const f32x4*)(p))
#define NTLOAD2(p) __builtin_nontemporal_load((const f32x2*)(p))

static __device__ __forceinline__ float dot2acc(h2 a, h2 b, float c) {
#if __has_builtin(__builtin_amdgcn_fdot2)
    return __builtin_amdgcn_fdot2(a, b, c, false);
#else
    return c + (float)a.x * (float)b.x + (float)a.y * (float)b.y;
#endif
}

__global__ __launch_bounds__(512) void natt_offset_kernel(
    const float* __restrict__ xq,
    const float* __restrict__ xk,
    float* __restrict__ out)
{
    __shared__ __align__(16) float kt[TILE_SLOTS];

    const int tid = threadIdx.x;
    // XCD swizzle: bid&7 = XCD; contiguous 64-row y-slab (8 y-tiles) per XCD.
    const int bid = blockIdx.x;
    const int r8  = bid & 7;
    const int u   = bid >> 3;
    const int yt  = r8 * 4 + (u & 3);   // 0..31
    const int rst = u >> 2;
    const int xt  = rst & 7;            // 0..7
    const int b   = rst >> 3;           // 0..3

    const int Y0 = yt * TY;
    const int X0 = xt * XT;
    const bool interior = (yt != 0) && (yt != 31) && (xt != 0) && (xt != 7);

    const int w    = tid >> 6;          // wave 0..7
    const int h    = w & 3;             // head
    const int wrb  = (w >> 2) * 4;      // row-half base: 0 or 4
    const int lane = tid & 63;
    const int row  = lane >> 4;         // 0..3
    const int qx   = lane & 15;         // 0..15 (2 px each)
    const int y    = Y0 + wrb + row;
    const int x0   = X0 + qx * 2;

    const size_t plane = (size_t)Hdim * Wdim;
    const float scale = 0.35355339059327373f;   // 8^-0.5

    // ---- block-cooperative staging: 1920 float4 jobs over 512 threads.
    // Job j: c4=j%10 (x-chunk), t=j/10: rw=t%12 (tile row), p=t/12 (pair).
    // Pair p = 4*d2+h -> channels 8*d2+h (A) and +4 (B). LDS f16x2 packed.
    {
        const float* kb = xk + (size_t)b * Cdim * plane;
        if (interior) {
            #pragma unroll
            for (int it = 0; it < 4; ++it) {
                const int j = tid + it * 512;
                if (j < NJOBS) {
                    const int c4 = j % 10;
                    const int t  = j / 10;
                    const int rw = t % TROWS;
                    const int p  = t / TROWS;            // pair 0..15
                    const int c0 = 8 * (p >> 2) + (p & 3);
                    const int yr = Y0 - AMP + rw;        // 6..249: no clamp
                    const int xs = X0 - 6 + c4 * 4;      // 26..222: no clamp
                    const float* pa = kb + (size_t)c0 * plane + (size_t)yr * Wdim + xs;
                    const f32x4 va = NTLOAD4(pa);
                    const f32x4 vb = NTLOAD4(pa + 4 * plane);
                    const float a[4]  = {va.x, va.y, va.z, va.w};
                    const float bb[4] = {vb.x, vb.y, vb.z, vb.w};
                    float o[4];
                    #pragma unroll
                    for (int k2 = 0; k2 < 4; ++k2) {
                        h2 pk;
                        pk.x = (_Float16)a[k2];
                        pk.y = (_Float16)bb[k2];
                        o[k2] = __builtin_bit_cast(float, pk);
                    }
                    *(float4*)(kt + p * PAIR_STRIDE + rw * TPOS + c4 * 4) =
                        make_float4(o[0], o[1], o[2], o[3]);
                }
            }
        } else {
            // clamped loads + STATIC-index rotate (sh in {-6,-2,0,+2}; R3
            // post-mortem: runtime-indexed arrays spill to scratch).
            #pragma unroll
            for (int it = 0; it < 4; ++it) {
                const int j = tid + it * 512;
                if (j < NJOBS) {
                    const int c4 = j % 10;
                    const int t  = j / 10;
                    const int rw = t % TROWS;
                    const int p  = t / TROWS;
                    const int c0 = 8 * (p >> 2) + (p & 3);
                    int yr = Y0 - AMP + rw;
                    yr = yr < 0 ? 0 : (yr > Hdim - 1 ? Hdim - 1 : yr);
                    const int xs = X0 - 6 + c4 * 4;
                    const int xc = xs < 0 ? 0 : (xs > Wdim - 4 ? Wdim - 4 : xs);
                    const int sh = xs - xc;              // -6, -2, 0, +2
                    const float* pa = kb + (size_t)c0 * plane + (size_t)yr * Wdim + xc;
                    const f32x4 va = NTLOAD4(pa);
                    const f32x4 vb = NTLOAD4(pa + 4 * plane);
                    const float a[4]  = {va.x, va.y, va.z, va.w};
                    const float bb[4] = {vb.x, vb.y, vb.z, vb.w};
                    float o[4];
                    #pragma unroll
                    for (int k2 = 0; k2 < 4; ++k2) {
                        const int ip2 = (k2 + 2 > 3) ? 3 : k2 + 2;
                        const int im2 = (k2 - 2 < 0) ? 0 : k2 - 2;
                        const float fa = sh == 0 ? a[k2]
                                       : (sh == 2 ? a[ip2] : (sh == -2 ? a[im2] : a[0]));
                        const float fb = sh == 0 ? bb[k2]
                                       : (sh == 2 ? bb[ip2] : (sh == -2 ? bb[im2] : bb[0]));
                        h2 pk; pk.x = (_Float16)fa; pk.y = (_Float16)fb;
                        o[k2] = __builtin_bit_cast(float, pk);
                    }
                    *(float4*)(kt + p * PAIR_STRIDE + rw * TPOS + c4 * 4) =
                        make_float4(o[0], o[1], o[2], o[3]);
                }
            }
        }
    }

    // ---- q fragments for this head/row-half, packed f16x2 by d-pair, 2 px each
    const float* qb = xq + (size_t)b * Cdim * plane + (size_t)y * Wdim + x0;
    h2 q2[4][2];
    #pragma unroll
    for (int d2 = 0; d2 < 4; ++d2) {
        const f32x2 qa = NTLOAD2(qb + (size_t)((2 * d2)     * NH + h) * plane);
        const f32x2 qc = NTLOAD2(qb + (size_t)((2 * d2 + 1) * NH + h) * plane);
        const float qa2[2] = {qa.x, qa.y};
        const float qc2[2] = {qc.x, qc.y};
        #pragma unroll
        for (int p = 0; p < 2; ++p) {
            q2[d2][p].x = (_Float16)(qa2[p] * scale);
            q2[d2][p].y = (_Float16)(qc2[p] * scale);
        }
    }

    // staging is cross-wave now (waves w and w+4 share head pairs): barrier.
    __syncthreads();

    float Z[2]  = {0.f, 0.f};
    float sx[2] = {0.f, 0.f};
    float sy[2] = {0.f, 0.f};

    #pragma unroll
    for (int r = 0; r < KS; ++r) {
        float dot[KS][2];
        #pragma unroll
        for (int dj = 0; dj < KS; ++dj) { dot[dj][0] = 0.f; dot[dj][1] = 0.f; }

        #pragma unroll
        for (int d2 = 0; d2 < 4; ++d2) {
            // 6-pos window: pos qx*2+4 .. qx*2+9, three aligned b64s
            const float* wp = kt + ((d2 << 2) | h) * PAIR_STRIDE
                                 + (wrb + row + r) * TPOS + (qx * 2 + 4);
            const float2 wa = *(const float2*)wp;
            const float2 wb = *(const float2*)(wp + 2);
            const float2 wc = *(const float2*)(wp + 4);
            const float wf[6] = {wa.x, wa.y, wb.x, wb.y, wc.x, wc.y};
            h2 wreg[6];
            #pragma unroll
            for (int k2 = 0; k2 < 6; ++k2) wreg[k2] = __builtin_bit_cast(h2, wf[k2]);
            #pragma unroll
            for (int dj = 0; dj < KS; ++dj) {
                #pragma unroll
                for (int p = 0; p < 2; ++p)
                    dot[dj][p] = dot2acc(q2[d2][p], wreg[p + dj], dot[dj][p]);
            }
        }

        const float fdi = (float)(r - AMP);
        if (interior) {                        // block-uniform: no masks
            #pragma unroll
            for (int p = 0; p < 2; ++p) {
                float e[KS];
                #pragma unroll
                for (int dj = 0; dj < KS; ++dj) e[dj] = __expf(dot[dj][p]);
                const float er = ((e[0] + e[1]) + (e[2] + e[3])) + e[4];
                Z[p]  += er;
                sx[p] += fdi * er;
                sy[p] += (e[3] - e[1]) + 2.f * (e[4] - e[0]);
            }
        } else {
            const int yy = y + r - AMP;
            const bool rowok = (yy >= 0) && (yy < Hdim);
            #pragma unroll
            for (int p = 0; p < 2; ++p) {
                float e[KS];
                #pragma unroll
                for (int dj = 0; dj < KS; ++dj) {
                    const int xx = x0 + p + dj - AMP;
                    const bool ok = rowok && (xx >= 0) && (xx < Wdim);
                    e[dj] = ok ? __expf(dot[dj][p]) : 0.f;
                }
                const float er = ((e[0] + e[1]) + (e[2] + e[3])) + e[4];
                Z[p]  += er;
                sx[p] += fdi * er;
                sy[p] += (e[3] - e[1]) + 2.f * (e[4] - e[0]);
            }
        }
    }

    // ---- head mean through LDS (reuse kt; barrier before and after red writes).
    __syncthreads();
    float* red = kt;                     // 4 heads x 2 ch x 256 px = 2048 floats
    const int pxl = (wrb + row) * XT + qx * 2;
    {
        const float i0 = 1.f / Z[0], i1 = 1.f / Z[1];
        *(float2*)(red + (h * 2 + 0) * (XT * TY) + pxl) =
            make_float2(sx[0]*i0, sx[1]*i1);
        *(float2*)(red + (h * 2 + 1) * (XT * TY) + pxl) =
            make_float2(sy[0]*i0, sy[1]*i1);
    }
    __syncthreads();

    if (w < 4) {                         // wave w: ch=w&1, row-half=(w>>1)*4
        const int ch  = w & 1;
        const int rr  = (w >> 1) * 4 + row;
        const int px2 = rr * XT + qx * 2;
        float acc[2] = {0.f, 0.f};
        #pragma unroll
        for (int hh = 0; hh < NH; ++hh) {
            const float2 v = *(const float2*)(red + (hh * 2 + ch) * (XT * TY) + px2);
            acc[0] += v.x; acc[1] += v.y;
        }
        f32x2 ov; ov.x = acc[0] * 0.25f; ov.y = acc[1] * 0.25f;
        __builtin_nontemporal_store(ov,
            (f32x2*)(out + ((size_t)b * 2 + ch) * plane + (size_t)(Y0 + rr) * Wdim + x0));
    }
}

extern "C" void kernel_launch(void* const* d_in, const int* in_sizes, int n_in,
                              void* d_out, int out_size, void* d_ws, size_t ws_size,
                              hipStream_t stream) {
    const float* xq = (const float*)d_in[0];
    const float* xk = (const float*)d_in[1];
    float* out = (float*)d_out;

    // 32 y-tiles x 8 x-tiles x 4 batches = 1024 blocks x 512 threads
    natt_offset_kernel<<<dim3(1024, 1, 1), dim3(512, 1, 1), 0, stream>>>(xq, xk, out);
}

// Round 8
// 99.697 us; speedup vs baseline: 1.0993x; 1.0993x over previous
//
#include <hip/hip_runtime.h>

// Problem constants: B=4, C=32, H=W=256, heads=4, head_dim=8, amp=2.
#define Bdim 4
#define Cdim 32
#define NH   4
#define HD   8
#define Hdim 256
#define Wdim 256
#define AMP  2
#define KS   5

// R8: exact revert to R6 (best measured: total 100.5us, kernel ~18.1us).
// R7's non-temporal loads regressed kernel 18->28us: nt (evict-first) killed
// the L2/L3 service of k y-halo re-reads across adjacent same-XCD blocks.
// Allocation is net-positive; keep normal cached loads.
// History: R2 flat TY=4 17.8 | R3-5 manual pipeline 27-51 (spill/MLP loss) |
// R6 TY=8 512thr 18.1 | R7 nt 27.6. Phase-aligned flat structure wins; ~1.3x
// above pure-BW floor (~92MB amplified reqs, mem ~14us + compute ~4us).
#define XT    32
#define TY    8
#define TROWS 12                    // TY + 2*AMP
#define TPOS  40
#define NPAIRS 16                   // 4 heads * 4 d-pairs
#define PAIR_STRIDE (TROWS * TPOS)  // 480
#define TILE_SLOTS (NPAIRS * PAIR_STRIDE)   // 7680 * 4B = 30 KB
#define NJOBS (NPAIRS * TROWS * 10) // 1920 float4 staging jobs

typedef _Float16 h2 __attribute__((ext_vector_type(2)));

static __device__ __forceinline__ float dot2acc(h2 a, h2 b, float c) {
#if __has_builtin(__builtin_amdgcn_fdot2)
    return __builtin_amdgcn_fdot2(a, b, c, false);
#else
    return c + (float)a.x * (float)b.x + (float)a.y * (float)b.y;
#endif
}

__global__ __launch_bounds__(512) void natt_offset_kernel(
    const float* __restrict__ xq,
    const float* __restrict__ xk,
    float* __restrict__ out)
{
    __shared__ __align__(16) float kt[TILE_SLOTS];

    const int tid = threadIdx.x;
    // XCD swizzle: bid&7 = XCD; contiguous 64-row y-slab (8 y-tiles) per XCD.
    const int bid = blockIdx.x;
    const int r8  = bid & 7;
    const int u   = bid >> 3;
    const int yt  = r8 * 4 + (u & 3);   // 0..31
    const int rst = u >> 2;
    const int xt  = rst & 7;            // 0..7
    const int b   = rst >> 3;           // 0..3

    const int Y0 = yt * TY;
    const int X0 = xt * XT;
    const bool interior = (yt != 0) && (yt != 31) && (xt != 0) && (xt != 7);

    const int w    = tid >> 6;          // wave 0..7
    const int h    = w & 3;             // head
    const int wrb  = (w >> 2) * 4;      // row-half base: 0 or 4
    const int lane = tid & 63;
    const int row  = lane >> 4;         // 0..3
    const int qx   = lane & 15;         // 0..15 (2 px each)
    const int y    = Y0 + wrb + row;
    const int x0   = X0 + qx * 2;

    const size_t plane = (size_t)Hdim * Wdim;
    const float scale = 0.35355339059327373f;   // 8^-0.5

    // ---- block-cooperative staging: 1920 float4 jobs over 512 threads.
    // Job j: c4=j%10 (x-chunk), t=j/10: rw=t%12 (tile row), p=t/12 (pair).
    // Pair p = 4*d2+h -> channels 8*d2+h (A) and +4 (B). LDS f16x2 packed.
    {
        const float* kb = xk + (size_t)b * Cdim * plane;
        if (interior) {
            #pragma unroll
            for (int it = 0; it < 4; ++it) {
                const int j = tid + it * 512;
                if (j < NJOBS) {
                    const int c4 = j % 10;
                    const int t  = j / 10;
                    const int rw = t % TROWS;
                    const int p  = t / TROWS;            // pair 0..15
                    const int c0 = 8 * (p >> 2) + (p & 3);
                    const int yr = Y0 - AMP + rw;        // 6..249: no clamp
                    const int xs = X0 - 6 + c4 * 4;      // 26..222: no clamp
                    const float* pa = kb + (size_t)c0 * plane + (size_t)yr * Wdim + xs;
                    const float4 va = *(const float4*)pa;
                    const float4 vb = *(const float4*)(pa + 4 * plane);
                    const float a[4]  = {va.x, va.y, va.z, va.w};
                    const float bb[4] = {vb.x, vb.y, vb.z, vb.w};
                    float o[4];
                    #pragma unroll
                    for (int k2 = 0; k2 < 4; ++k2) {
                        h2 pk;
                        pk.x = (_Float16)a[k2];
                        pk.y = (_Float16)bb[k2];
                        o[k2] = __builtin_bit_cast(float, pk);
                    }
                    *(float4*)(kt + p * PAIR_STRIDE + rw * TPOS + c4 * 4) =
                        make_float4(o[0], o[1], o[2], o[3]);
                }
            }
        } else {
            // clamped loads + STATIC-index rotate (sh in {-6,-2,0,+2}; R3
            // post-mortem: runtime-indexed arrays spill to scratch).
            #pragma unroll
            for (int it = 0; it < 4; ++it) {
                const int j = tid + it * 512;
                if (j < NJOBS) {
                    const int c4 = j % 10;
                    const int t  = j / 10;
                    const int rw = t % TROWS;
                    const int p  = t / TROWS;
                    const int c0 = 8 * (p >> 2) + (p & 3);
                    int yr = Y0 - AMP + rw;
                    yr = yr < 0 ? 0 : (yr > Hdim - 1 ? Hdim - 1 : yr);
                    const int xs = X0 - 6 + c4 * 4;
                    const int xc = xs < 0 ? 0 : (xs > Wdim - 4 ? Wdim - 4 : xs);
                    const int sh = xs - xc;              // -6, -2, 0, +2
                    const float* pa = kb + (size_t)c0 * plane + (size_t)yr * Wdim + xc;
                    const float4 va = *(const float4*)pa;
                    const float4 vb = *(const float4*)(pa + 4 * plane);
                    const float a[4]  = {va.x, va.y, va.z, va.w};
                    const float bb[4] = {vb.x, vb.y, vb.z, vb.w};
                    float o[4];
                    #pragma unroll
                    for (int k2 = 0; k2 < 4; ++k2) {
                        const int ip2 = (k2 + 2 > 3) ? 3 : k2 + 2;
                        const int im2 = (k2 - 2 < 0) ? 0 : k2 - 2;
                        const float fa = sh == 0 ? a[k2]
                                       : (sh == 2 ? a[ip2] : (sh == -2 ? a[im2] : a[0]));
                        const float fb = sh == 0 ? bb[k2]
                                       : (sh == 2 ? bb[ip2] : (sh == -2 ? bb[im2] : bb[0]));
                        h2 pk; pk.x = (_Float16)fa; pk.y = (_Float16)fb;
                        o[k2] = __builtin_bit_cast(float, pk);
                    }
                    *(float4*)(kt + p * PAIR_STRIDE + rw * TPOS + c4 * 4) =
                        make_float4(o[0], o[1], o[2], o[3]);
                }
            }
        }
    }

    // ---- q fragments for this head/row-half, packed f16x2 by d-pair, 2 px each
    const float* qb = xq + (size_t)b * Cdim * plane + (size_t)y * Wdim + x0;
    h2 q2[4][2];
    #pragma unroll
    for (int d2 = 0; d2 < 4; ++d2) {
        const float2 qa = *(const float2*)(qb + (size_t)((2 * d2)     * NH + h) * plane);
        const float2 qc = *(const float2*)(qb + (size_t)((2 * d2 + 1) * NH + h) * plane);
        const float qa2[2] = {qa.x, qa.y};
        const float qc2[2] = {qc.x, qc.y};
        #pragma unroll
        for (int p = 0; p < 2; ++p) {
            q2[d2][p].x = (_Float16)(qa2[p] * scale);
            q2[d2][p].y = (_Float16)(qc2[p] * scale);
        }
    }

    // staging is cross-wave (waves w and w+4 share head pairs): barrier.
    __syncthreads();

    float Z[2]  = {0.f, 0.f};
    float sx[2] = {0.f, 0.f};
    float sy[2] = {0.f, 0.f};

    #pragma unroll
    for (int r = 0; r < KS; ++r) {
        float dot[KS][2];
        #pragma unroll
        for (int dj = 0; dj < KS; ++dj) { dot[dj][0] = 0.f; dot[dj][1] = 0.f; }

        #pragma unroll
        for (int d2 = 0; d2 < 4; ++d2) {
            // 6-pos window: pos qx*2+4 .. qx*2+9, three aligned b64s
            const float* wp = kt + ((d2 << 2) | h) * PAIR_STRIDE
                                 + (wrb + row + r) * TPOS + (qx * 2 + 4);
            const float2 wa = *(const float2*)wp;
            const float2 wb = *(const float2*)(wp + 2);
            const float2 wc = *(const float2*)(wp + 4);
            const float wf[6] = {wa.x, wa.y, wb.x, wb.y, wc.x, wc.y};
            h2 wreg[6];
            #pragma unroll
            for (int k2 = 0; k2 < 6; ++k2) wreg[k2] = __builtin_bit_cast(h2, wf[k2]);
            #pragma unroll
            for (int dj = 0; dj < KS; ++dj) {
                #pragma unroll
                for (int p = 0; p < 2; ++p)
                    dot[dj][p] = dot2acc(q2[d2][p], wreg[p + dj], dot[dj][p]);
            }
        }

        const float fdi = (float)(r - AMP);
        if (interior) {                        // block-uniform: no masks
            #pragma unroll
            for (int p = 0; p < 2; ++p) {
                float e[KS];
                #pragma unroll
                for (int dj = 0; dj < KS; ++dj) e[dj] = __expf(dot[dj][p]);
                const float er = ((e[0] + e[1]) + (e[2] + e[3])) + e[4];
                Z[p]  += er;
                sx[p] += fdi * er;
                sy[p] += (e[3] - e[1]) + 2.f * (e[4] - e[0]);
            }
        } else {
            const int yy = y + r - AMP;
            const bool rowok = (yy >= 0) && (yy < Hdim);
            #pragma unroll
            for (int p = 0; p < 2; ++p) {
                float e[KS];
                #pragma unroll
                for (int dj = 0; dj < KS; ++dj) {
                    const int xx = x0 + p + dj - AMP;
                    const bool ok = rowok && (xx >= 0) && (xx < Wdim);
                    e[dj] = ok ? __expf(dot[dj][p]) : 0.f;
                }
                const float er = ((e[0] + e[1]) + (e[2] + e[3])) + e[4];
                Z[p]  += er;
                sx[p] += fdi * er;
                sy[p] += (e[3] - e[1]) + 2.f * (e[4] - e[0]);
            }
        }
    }

    // ---- head mean through LDS (reuse kt; barrier before and after red writes).
    __syncthreads();
    float* red = kt;                     // 4 heads x 2 ch x 256 px = 2048 floats
    const int pxl = (wrb + row) * XT + qx * 2;
    {
        const float i0 = 1.f / Z[0], i1 = 1.f / Z[1];
        *(float2*)(red + (h * 2 + 0) * (XT * TY) + pxl) =
            make_float2(sx[0]*i0, sx[1]*i1);
        *(float2*)(red + (h * 2 + 1) * (XT * TY) + pxl) =
            make_float2(sy[0]*i0, sy[1]*i1);
    }
    __syncthreads();

    if (w < 4) {                         // wave w: ch=w&1, row-half=(w>>1)*4
        const int ch  = w & 1;
        const int rr  = (w >> 1) * 4 + row;
        const int px2 = rr * XT + qx * 2;
        float acc[2] = {0.f, 0.f};
        #pragma unroll
        for (int hh = 0; hh < NH; ++hh) {
            const float2 v = *(const float2*)(red + (hh * 2 + ch) * (XT * TY) + px2);
            acc[0] += v.x; acc[1] += v.y;
        }
        *(float2*)(out + ((size_t)b * 2 + ch) * plane + (size_t)(Y0 + rr) * Wdim + x0) =
            make_float2(acc[0]*0.25f, acc[1]*0.25f);
    }
}

extern "C" void kernel_launch(void* const* d_in, const int* in_sizes, int n_in,
                              void* d_out, int out_size, void* d_ws, size_t ws_size,
                              hipStream_t stream) {
    const float* xq = (const float*)d_in[0];
    const float* xk = (const float*)d_in[1];
    float* out = (float*)d_out;

    // 32 y-tiles x 8 x-tiles x 4 batches = 1024 blocks x 512 threads
    natt_offset_kernel<<<dim3(1024, 1, 1), dim3(512, 1, 1), 0, stream>>>(xq, xk, out);
}